// Round 7
// baseline (446.735 us; speedup 1.0000x reference)
//
#include <hip/hip_runtime.h>
#include <hip/hip_fp16.h>
#include <math.h>

#define BLK 256
#define CBSH 10          // 1024 nodes per coarse bucket
#define CBN 1024
#define NCBC 128         // static LDS sizing (nbkt=98 for n=100k)
#define LC 112           // per-(block,bucket) LDS buffer entries; mean 64, ~6 sigma
#define CCAP 20000       // slab entries per coarse bucket; mean 16.3K, ~28 sigma

__device__ __forceinline__ float selu_f(float x) {
    const float kScale = 1.0507009873554805f;
    const float kAlpha = 1.6732632423543772f;
    return x > 0.0f ? kScale * x : kScale * kAlpha * expm1f(x);
}

__device__ __forceinline__ float2 h2f2(unsigned u) {
    __half2 h = *reinterpret_cast<__half2*>(&u);
    return __half22float2(h);
}
__device__ __forceinline__ void h8_set(float* a, uint4 v) {
    float2 f0 = h2f2(v.x), f1 = h2f2(v.y), f2 = h2f2(v.z), f3 = h2f2(v.w);
    a[0] = f0.x; a[1] = f0.y; a[2] = f1.x; a[3] = f1.y;
    a[4] = f2.x; a[5] = f2.y; a[6] = f3.x; a[7] = f3.y;
}
__device__ __forceinline__ void h8_add(float* a, uint4 v) {
    float2 f0 = h2f2(v.x), f1 = h2f2(v.y), f2 = h2f2(v.z), f3 = h2f2(v.w);
    a[0] += f0.x; a[1] += f0.y; a[2] += f1.x; a[3] += f1.y;
    a[4] += f2.x; a[5] += f2.y; a[6] += f3.x; a[7] += f3.y;
}

__global__ void k_zero(int* __restrict__ p, int n) {
    int i = blockIdx.x * BLK + threadIdx.x;
    if (i < n) p[i] = 0;
}

// LDS-staged coarse binning: 98 buckets x 1024 nodes. One global atomic per
// (block,bucket) flush reservation; dense 64-lane burst writes into the slab.
// pack = (src<<10) | (dst&1023), 27 bits.
__global__ void k_binA(const int* __restrict__ src, const int* __restrict__ dst,
                       int* __restrict__ gcnt, unsigned* __restrict__ slab,
                       int e, int nbkt) {
    __shared__ unsigned lbuf[NCBC * LC];
    __shared__ int lcnt[NCBC];
    int tid = threadIdx.x;
    for (int b = tid; b < NCBC; b += BLK) lcnt[b] = 0;
    __syncthreads();
    int per = (e + gridDim.x - 1) / gridDim.x;
    int lo = blockIdx.x * per;
    int hi = min(e, lo + per);
    for (int i = lo + tid; i < hi; i += BLK) {
        int s = src[i], d = dst[i];
        int b = d >> CBSH;
        unsigned pk = ((unsigned)s << CBSH) | (unsigned)(d & (CBN - 1));
        int pos = atomicAdd(&lcnt[b], 1);
        if (pos < LC) {
            lbuf[b * LC + pos] = pk;
        } else {  // rare overflow: direct global fallback
            int gp = atomicAdd(&gcnt[b], 1);
            if (gp < CCAP) slab[(size_t)b * CCAP + gp] = pk;
        }
    }
    __syncthreads();
    int wv = tid >> 6, lane = tid & 63;
    for (int b = wv; b < nbkt; b += 4) {
        int cnt = min(lcnt[b], LC);
        if (cnt == 0) continue;
        int base = 0;
        if (lane == 0) base = atomicAdd(&gcnt[b], cnt);
        base = __shfl(base, 0);
        for (int i = lane; i < cnt; i += 64) {
            int gp = base + i;
            if (gp < CCAP) slab[(size_t)b * CCAP + gp] = lbuf[b * LC + i];
        }
    }
}

// One block per coarse bucket: LDS histogram (1024 counters) -> deg.
__global__ void k_histB(const int* __restrict__ gcnt, const unsigned* __restrict__ slab,
                        int* __restrict__ deg, int n) {
    __shared__ int hist[CBN];
    int b = blockIdx.x, tid = threadIdx.x;
    for (int j = tid; j < CBN; j += BLK) hist[j] = 0;
    __syncthreads();
    int cnt = min(gcnt[b], CCAP);
    size_t base = (size_t)b * CCAP;
    for (int i = tid; i < cnt; i += BLK) atomicAdd(&hist[slab[base + i] & (CBN - 1)], 1);
    __syncthreads();
    int node0 = b << CBSH;
    for (int j = tid; j < CBN; j += BLK) {
        int node = node0 + j;
        if (node < n) deg[node] = hist[j];
    }
}

// Exclusive scan over deg, 3-kernel hierarchy (1024 items/block).
__global__ void k_scan1(const int* __restrict__ deg, int* __restrict__ rowptr,
                        int* __restrict__ bsums, int n) {
    __shared__ int lds[BLK];
    int tid = threadIdx.x;
    int idx = blockIdx.x * (BLK * 4) + tid * 4;
    int v0 = 0, v1 = 0, v2 = 0, v3 = 0;
    if (idx + 3 < n) {
        int4 t = *reinterpret_cast<const int4*>(deg + idx);
        v0 = t.x; v1 = t.y; v2 = t.z; v3 = t.w;
    } else {
        if (idx < n) v0 = deg[idx];
        if (idx + 1 < n) v1 = deg[idx + 1];
        if (idx + 2 < n) v2 = deg[idx + 2];
        if (idx + 3 < n) v3 = deg[idx + 3];
    }
    int tot = v0 + v1 + v2 + v3;
    lds[tid] = tot;
    __syncthreads();
    int val = tot;
    for (int off = 1; off < BLK; off <<= 1) {
        int t2 = (tid >= off) ? lds[tid - off] : 0;
        __syncthreads();
        val += t2;
        lds[tid] = val;
        __syncthreads();
    }
    int excl = val - tot;
    if (idx < n) rowptr[idx] = excl;
    if (idx + 1 < n) rowptr[idx + 1] = excl + v0;
    if (idx + 2 < n) rowptr[idx + 2] = excl + v0 + v1;
    if (idx + 3 < n) rowptr[idx + 3] = excl + v0 + v1 + v2;
    if (tid == BLK - 1) bsums[blockIdx.x] = val;
}

__global__ void k_scan2(int* __restrict__ bsums, int nb) {  // nb <= BLK
    __shared__ int lds[BLK];
    int tid = threadIdx.x;
    int v = (tid < nb) ? bsums[tid] : 0;
    lds[tid] = v;
    __syncthreads();
    int val = v;
    for (int off = 1; off < BLK; off <<= 1) {
        int t2 = (tid >= off) ? lds[tid - off] : 0;
        __syncthreads();
        val += t2;
        lds[tid] = val;
        __syncthreads();
    }
    if (tid < nb) bsums[tid] = val - v;  // exclusive
}

__global__ void k_scan3(int* __restrict__ rowptr, const int* __restrict__ bsums,
                        const int* __restrict__ deg, float* __restrict__ dinv,
                        int n, int e) {
    int i = blockIdx.x * BLK + threadIdx.x;
    if (i >= n) return;
    int r = rowptr[i] + bsums[i >> 10];
    rowptr[i] = r;
    dinv[i] = rsqrtf((float)(deg[i] + 1));  // +1 self-loop
    if (i == n - 1) rowptr[n] = e;          // sentinel
}

// One block per coarse bucket: LDS cursors; csr writes land in a ~65KB window.
__global__ void k_placeC(const int* __restrict__ gcnt, const unsigned* __restrict__ slab,
                         const int* __restrict__ rowptr, int* __restrict__ csr, int n) {
    __shared__ int cur[CBN];
    int b = blockIdx.x, tid = threadIdx.x;
    int node0 = b << CBSH;
    for (int j = tid; j < CBN; j += BLK) {
        int node = node0 + j;
        cur[j] = (node < n) ? rowptr[node] : 0;
    }
    __syncthreads();
    int cnt = min(gcnt[b], CCAP);
    size_t base = (size_t)b * CCAP;
    for (int i = tid; i < cnt; i += BLK) {
        unsigned p = slab[base + i];
        int pos = atomicAdd(&cur[p & (CBN - 1)], 1);
        csr[pos] = (int)(p >> CBSH);
    }
}

// hs[i,0..F) = fp16( dinv[i] * (act(xin[i,0..K)) @ W) ); rows at SO halves, zero-pad to F8.
template <int K, int KP, int F, int SI, int SO, bool FUSE_IN>
__global__ void k_gemm(const float* __restrict__ xin, const float* __restrict__ W,
                       const float* __restrict__ bprev, const float* __restrict__ dinv,
                       __half* __restrict__ hs, int n) {
    constexpr int F8 = (F + 7) & ~7;
    int i = blockIdx.x * BLK + threadIdx.x;
    if (i >= n) return;
    const float* xr = xin + (size_t)i * SI;
    float di = dinv[i];
    float accf[F8];
#pragma unroll
    for (int f = 0; f < F8; ++f) accf[f] = 0.0f;
#pragma unroll
    for (int k4 = 0; k4 < KP / 4; ++k4) {
        float4 xv = *reinterpret_cast<const float4*>(xr + k4 * 4);
        float xs4[4] = {xv.x, xv.y, xv.z, xv.w};
#pragma unroll
        for (int j = 0; j < 4; ++j) {
            const int k = k4 * 4 + j;
            if (k < K) {
                float xval = xs4[j];
                if (FUSE_IN) xval = selu_f(di * xval + bprev[k]);  // prev-layer epilogue
#pragma unroll
                for (int f = 0; f < F; ++f) accf[f] = fmaf(xval, W[k * F + f], accf[f]);
            }
        }
    }
#pragma unroll
    for (int f = 0; f < F; ++f) accf[f] *= di;
    __half2* ro2 = reinterpret_cast<__half2*>(hs + (size_t)i * SO);
#pragma unroll
    for (int f2 = 0; f2 < F8 / 2; ++f2)
        ro2[f2] = __float22half2_rn(make_float2(accf[2 * f2], accf[2 * f2 + 1]));
}

// CSR gather on fp16 rows: G lanes/node, lane chunk = uint4 (8 halves), fp32 accum.
template <int F, int S /*halves*/, int G, int SOUT, bool LAST>
__global__ void k_agg(const int* __restrict__ rowptr, const int* __restrict__ csr,
                      const __half* __restrict__ hs, float* __restrict__ out,
                      const float* __restrict__ dinv, const float* __restrict__ bias,
                      int n) {
    constexpr int NPW = 64 / G;
    constexpr int CH = ((F + 7) & ~7) / 8;
    int lane = threadIdx.x & 63;
    int g = lane / G;
    int fl = lane & (G - 1);
    int wid = (blockIdx.x * BLK + threadIdx.x) >> 6;
    int d = wid * NPW + g;
    if (d >= n || fl >= CH) return;
    int beg = rowptr[d], end = rowptr[d + 1];
    auto rowp = [&](int r) {
        return reinterpret_cast<const uint4*>(hs + (size_t)r * S) + fl;
    };
    float s0[8], s1[8] = {0}, s2[8] = {0}, s3[8] = {0};
    h8_set(s0, *rowp(d));  // self
    int p = beg;
    for (; p + 4 <= end; p += 4) {
        int e0 = csr[p], e1 = csr[p + 1], e2 = csr[p + 2], e3 = csr[p + 3];
        uint4 v0 = *rowp(e0), v1 = *rowp(e1), v2 = *rowp(e2), v3 = *rowp(e3);
        h8_add(s0, v0); h8_add(s1, v1); h8_add(s2, v2); h8_add(s3, v3);
    }
    for (; p < end; ++p) h8_add(s0, *rowp(csr[p]));
    float sum[8];
#pragma unroll
    for (int j = 0; j < 8; ++j) sum[j] = (s0[j] + s1[j]) + (s2[j] + s3[j]);
    if (LAST) {
        float dv = dinv[d];
        float r[8];
#pragma unroll
        for (int j = 0; j < 8; ++j) {
            int col = fl * 8 + j;
            r[j] = (col < F) ? selu_f(dv * sum[j] + bias[col]) : 0.0f;
        }
        float* op = out + (size_t)d * F + fl * 8;
        *reinterpret_cast<float4*>(op) = make_float4(r[0], r[1], r[2], r[3]);
        if (fl * 8 + 4 < F)
            *reinterpret_cast<float4*>(op + 4) = make_float4(r[4], r[5], r[6], r[7]);
    } else {
        float* op = out + (size_t)d * SOUT + fl * 8;
        *reinterpret_cast<float4*>(op) = make_float4(sum[0], sum[1], sum[2], sum[3]);
        *reinterpret_cast<float4*>(op + 4) = make_float4(sum[4], sum[5], sum[6], sum[7]);
    }
}

extern "C" void kernel_launch(void* const* d_in, const int* in_sizes, int n_in,
                              void* d_out, int out_size, void* d_ws, size_t ws_size,
                              hipStream_t stream) {
    const float* x = (const float*)d_in[0];
    const int* ei = (const int*)d_in[1];  // int32 on device
    const float* W1 = (const float*)d_in[2];
    const float* b1 = (const float*)d_in[3];
    const float* W2 = (const float*)d_in[4];
    const float* b2 = (const float*)d_in[5];
    const float* W3 = (const float*)d_in[6];
    const float* b3 = (const float*)d_in[7];
    const float* W4 = (const float*)d_in[8];
    const float* b4 = (const float*)d_in[9];

    int n = in_sizes[0] / 128;
    int e = in_sizes[1] / 2;
    const int* s32 = ei;
    const int* d32 = ei + e;
    int nbkt = (n + CBN - 1) >> CBSH;  // 98 for n=100k (<= NCBC)

    char* w = (char*)d_ws;
    auto alloc = [&](size_t bytes) {
        char* p = w;
        w += (bytes + 255) & ~(size_t)255;
        return p;
    };
    int* deg = (int*)alloc((size_t)n * 4);
    int* rowptr = (int*)alloc(((size_t)n + 1) * 4);
    int* bsums = (int*)alloc((size_t)BLK * 4);
    float* dinv = (float*)alloc((size_t)n * 4);
    int* csr = (int*)alloc((size_t)e * 4);
    int* gcnt = (int*)alloc((size_t)NCBC * 4);
    __half* bufA = (__half*)alloc((size_t)n * 64 * 2);  // hs (max stride 64 halves); aliases slab
    float* bufB = (float*)alloc((size_t)n * 32 * 4);    // agg out / gemm in (fp32)
    unsigned* slab = (unsigned*)bufA;  // nbkt*CCAP*4 = 7.84MB <= 12.8MB

    int nb = (n + BLK - 1) / BLK;
    int nb_scan = (n + BLK * 4 - 1) / (BLK * 4);  // 98 (<= 256)

    // CSR build: LDS-staged coarse bin -> hist -> scan -> place
    k_zero<<<1, BLK, 0, stream>>>(gcnt, NCBC);
    k_binA<<<256, BLK, 0, stream>>>(s32, d32, gcnt, slab, e, nbkt);
    k_histB<<<nbkt, BLK, 0, stream>>>(gcnt, slab, deg, n);
    k_scan1<<<nb_scan, BLK, 0, stream>>>(deg, rowptr, bsums, n);
    k_scan2<<<1, BLK, 0, stream>>>(bsums, nb_scan);
    k_scan3<<<nb, BLK, 0, stream>>>(rowptr, bsums, deg, dinv, n, e);
    k_placeC<<<nbkt, BLK, 0, stream>>>(gcnt, slab, rowptr, csr, n);

    // agg grids: nodes/block = 4 waves * (64/G)
    int ab1 = (n + 127) / 128;  // G=2
    int ab2 = (n + 63) / 64;    // G=4
    int ab4 = (n + 31) / 32;    // G=8

    // layer 1: x[.,128] @ W1 -> hs1 fp16 (stride 16h); agg -> bufB fp32 (stride 16)
    k_gemm<128, 128, 15, 128, 16, false><<<nb, BLK, 0, stream>>>(x, W1, nullptr, dinv, bufA, n);
    k_agg<15, 16, 2, 16, false><<<ab1, BLK, 0, stream>>>(rowptr, csr, bufA, bufB, dinv, nullptr, n);

    // layer 2: hs2 stride 32h; agg out stride 32
    k_gemm<15, 16, 20, 16, 32, true><<<nb, BLK, 0, stream>>>(bufB, W2, b1, dinv, bufA, n);
    k_agg<20, 32, 4, 32, false><<<ab2, BLK, 0, stream>>>(rowptr, csr, bufA, bufB, dinv, nullptr, n);

    // layer 3
    k_gemm<20, 20, 27, 32, 32, true><<<nb, BLK, 0, stream>>>(bufB, W3, b2, dinv, bufA, n);
    k_agg<27, 32, 4, 32, false><<<ab2, BLK, 0, stream>>>(rowptr, csr, bufA, bufB, dinv, nullptr, n);

    // layer 4: hs4 stride 64h; agg fuses final epilogue -> d_out fp32
    k_gemm<27, 28, 36, 32, 64, true><<<nb, BLK, 0, stream>>>(bufB, W4, b3, dinv, bufA, n);
    k_agg<36, 64, 8, 36, true><<<ab4, BLK, 0, stream>>>(rowptr, csr, bufA, (float*)d_out, dinv, b4, n);
}

// Round 8
// 283.248 us; speedup vs baseline: 1.5772x; 1.5772x over previous
//
#include <hip/hip_runtime.h>
#include <hip/hip_fp16.h>
#include <math.h>

#define BLK 256
#define CBSH 10          // 1024 nodes per coarse bucket
#define CBN 1024
#define NCBC 128         // static LDS sizing (nbkt=98 for n=100k)
#define NB2 512          // blocks for count/scatter passes

__device__ __forceinline__ float selu_f(float x) {
    const float kScale = 1.0507009873554805f;
    const float kAlpha = 1.6732632423543772f;
    return x > 0.0f ? kScale * x : kScale * kAlpha * expm1f(x);
}

__device__ __forceinline__ float2 h2f2(unsigned u) {
    __half2 h = *reinterpret_cast<__half2*>(&u);
    return __half22float2(h);
}
__device__ __forceinline__ void h8_set(float* a, uint4 v) {
    float2 f0 = h2f2(v.x), f1 = h2f2(v.y), f2 = h2f2(v.z), f3 = h2f2(v.w);
    a[0] = f0.x; a[1] = f0.y; a[2] = f1.x; a[3] = f1.y;
    a[4] = f2.x; a[5] = f2.y; a[6] = f3.x; a[7] = f3.y;
}
__device__ __forceinline__ void h8_add(float* a, uint4 v) {
    float2 f0 = h2f2(v.x), f1 = h2f2(v.y), f2 = h2f2(v.z), f3 = h2f2(v.w);
    a[0] += f0.x; a[1] += f0.y; a[2] += f1.x; a[3] += f1.y;
    a[4] += f2.x; a[5] += f2.y; a[6] += f3.x; a[7] += f3.y;
}

// Pass A: per-block histogram over coarse buckets -> H[block][bucket]
__global__ void k_cnt(const int* __restrict__ dst, int* __restrict__ H, int e, int nbkt) {
    __shared__ int hist[NCBC];
    int tid = threadIdx.x;
    for (int b = tid; b < nbkt; b += BLK) hist[b] = 0;
    __syncthreads();
    int per = (e + NB2 - 1) / NB2;
    int lo = blockIdx.x * per;
    int hi = min(e, lo + per);
    for (int i = lo + tid; i < hi; i += BLK) atomicAdd(&hist[dst[i] >> CBSH], 1);
    __syncthreads();
    for (int b = tid; b < nbkt; b += BLK) H[blockIdx.x * nbkt + b] = hist[b];
}

// Column totals + exclusive scan over buckets -> bstart[nbkt+1]
__global__ void k_bsum(const int* __restrict__ H, int* __restrict__ bstart, int nbkt, int e) {
    __shared__ int tot[NCBC];
    int tid = threadIdx.x;
    for (int b = tid; b < nbkt; b += BLK) {
        int s = 0;
        for (int i = 0; i < NB2; ++i) s += H[i * nbkt + b];
        tot[b] = s;
    }
    __syncthreads();
    if (tid == 0) {
        int acc = 0;
        for (int b = 0; b < nbkt; ++b) {
            bstart[b] = acc;
            acc += tot[b];
        }
        bstart[nbkt] = acc;  // == e
    }
}

// Per-bucket exclusive scan over blocks (in-place): H[i][b] <- bstart[b] + sum_{i'<i} H[i'][b]
__global__ void k_off(int* __restrict__ H, const int* __restrict__ bstart, int nbkt) {
    __shared__ int lds[BLK];
    int b = blockIdx.x, tid = threadIdx.x;
    int v0 = H[(2 * tid) * nbkt + b];
    int v1 = H[(2 * tid + 1) * nbkt + b];
    int pair = v0 + v1;
    lds[tid] = pair;
    __syncthreads();
    int val = pair;
    for (int off = 1; off < BLK; off <<= 1) {
        int t2 = (tid >= off) ? lds[tid - off] : 0;
        __syncthreads();
        val += t2;
        lds[tid] = val;
        __syncthreads();
    }
    int excl = val - pair + bstart[b];
    H[(2 * tid) * nbkt + b] = excl;
    H[(2 * tid + 1) * nbkt + b] = excl + v0;
}

// Pass B: re-read edges, place into exact per-(block,bucket) regions via LDS cursors.
// pack = (src<<10) | (dst&1023)
__global__ void k_scatter2(const int* __restrict__ src, const int* __restrict__ dst,
                           const int* __restrict__ H, unsigned* __restrict__ slab,
                           int e, int nbkt) {
    __shared__ int cur[NCBC];
    int tid = threadIdx.x;
    for (int b = tid; b < nbkt; b += BLK) cur[b] = H[blockIdx.x * nbkt + b];
    __syncthreads();
    int per = (e + NB2 - 1) / NB2;
    int lo = blockIdx.x * per;
    int hi = min(e, lo + per);
    for (int i = lo + tid; i < hi; i += BLK) {
        int s = src[i], d = dst[i];
        int b = d >> CBSH;
        int pos = atomicAdd(&cur[b], 1);
        slab[pos] = ((unsigned)s << CBSH) | (unsigned)(d & (CBN - 1));
    }
}

// One block per coarse bucket: LDS histogram (1024 counters) -> deg.
__global__ void k_histB(const int* __restrict__ bstart, const unsigned* __restrict__ slab,
                        int* __restrict__ deg, int n) {
    __shared__ int hist[CBN];
    int b = blockIdx.x, tid = threadIdx.x;
    for (int j = tid; j < CBN; j += BLK) hist[j] = 0;
    __syncthreads();
    int lo = bstart[b], hi = bstart[b + 1];
    for (int i = lo + tid; i < hi; i += BLK) atomicAdd(&hist[slab[i] & (CBN - 1)], 1);
    __syncthreads();
    int node0 = b << CBSH;
    for (int j = tid; j < CBN; j += BLK) {
        int node = node0 + j;
        if (node < n) deg[node] = hist[j];
    }
}

// Exclusive scan over deg, 3-kernel hierarchy (1024 items/block).
__global__ void k_scan1(const int* __restrict__ deg, int* __restrict__ rowptr,
                        int* __restrict__ bsums, int n) {
    __shared__ int lds[BLK];
    int tid = threadIdx.x;
    int idx = blockIdx.x * (BLK * 4) + tid * 4;
    int v0 = 0, v1 = 0, v2 = 0, v3 = 0;
    if (idx + 3 < n) {
        int4 t = *reinterpret_cast<const int4*>(deg + idx);
        v0 = t.x; v1 = t.y; v2 = t.z; v3 = t.w;
    } else {
        if (idx < n) v0 = deg[idx];
        if (idx + 1 < n) v1 = deg[idx + 1];
        if (idx + 2 < n) v2 = deg[idx + 2];
        if (idx + 3 < n) v3 = deg[idx + 3];
    }
    int tot = v0 + v1 + v2 + v3;
    lds[tid] = tot;
    __syncthreads();
    int val = tot;
    for (int off = 1; off < BLK; off <<= 1) {
        int t2 = (tid >= off) ? lds[tid - off] : 0;
        __syncthreads();
        val += t2;
        lds[tid] = val;
        __syncthreads();
    }
    int excl = val - tot;
    if (idx < n) rowptr[idx] = excl;
    if (idx + 1 < n) rowptr[idx + 1] = excl + v0;
    if (idx + 2 < n) rowptr[idx + 2] = excl + v0 + v1;
    if (idx + 3 < n) rowptr[idx + 3] = excl + v0 + v1 + v2;
    if (tid == BLK - 1) bsums[blockIdx.x] = val;
}

__global__ void k_scan2(int* __restrict__ bsums, int nb) {  // nb <= BLK
    __shared__ int lds[BLK];
    int tid = threadIdx.x;
    int v = (tid < nb) ? bsums[tid] : 0;
    lds[tid] = v;
    __syncthreads();
    int val = v;
    for (int off = 1; off < BLK; off <<= 1) {
        int t2 = (tid >= off) ? lds[tid - off] : 0;
        __syncthreads();
        val += t2;
        lds[tid] = val;
        __syncthreads();
    }
    if (tid < nb) bsums[tid] = val - v;  // exclusive
}

__global__ void k_scan3(int* __restrict__ rowptr, const int* __restrict__ bsums,
                        const int* __restrict__ deg, float* __restrict__ dinv,
                        int n, int e) {
    int i = blockIdx.x * BLK + threadIdx.x;
    if (i >= n) return;
    int r = rowptr[i] + bsums[i >> 10];
    rowptr[i] = r;
    dinv[i] = rsqrtf((float)(deg[i] + 1));  // +1 self-loop
    if (i == n - 1) rowptr[n] = e;          // sentinel
}

// One block per coarse bucket: LDS cursors; csr writes land in a ~65KB window.
__global__ void k_placeC(const int* __restrict__ bstart, const unsigned* __restrict__ slab,
                         const int* __restrict__ rowptr, int* __restrict__ csr, int n) {
    __shared__ int cur[CBN];
    int b = blockIdx.x, tid = threadIdx.x;
    int node0 = b << CBSH;
    for (int j = tid; j < CBN; j += BLK) {
        int node = node0 + j;
        cur[j] = (node < n) ? rowptr[node] : 0;
    }
    __syncthreads();
    int lo = bstart[b], hi = bstart[b + 1];
    for (int i = lo + tid; i < hi; i += BLK) {
        unsigned p = slab[i];
        int pos = atomicAdd(&cur[p & (CBN - 1)], 1);
        csr[pos] = (int)(p >> CBSH);
    }
}

// hs[i,0..F) = fp16( dinv[i] * (act(xin[i,0..K)) @ W) ); rows at SO halves, zero-pad to F8.
template <int K, int KP, int F, int SI, int SO, bool FUSE_IN>
__global__ void k_gemm(const float* __restrict__ xin, const float* __restrict__ W,
                       const float* __restrict__ bprev, const float* __restrict__ dinv,
                       __half* __restrict__ hs, int n) {
    constexpr int F8 = (F + 7) & ~7;
    int i = blockIdx.x * BLK + threadIdx.x;
    if (i >= n) return;
    const float* xr = xin + (size_t)i * SI;
    float di = dinv[i];
    float accf[F8];
#pragma unroll
    for (int f = 0; f < F8; ++f) accf[f] = 0.0f;
#pragma unroll
    for (int k4 = 0; k4 < KP / 4; ++k4) {
        float4 xv = *reinterpret_cast<const float4*>(xr + k4 * 4);
        float xs4[4] = {xv.x, xv.y, xv.z, xv.w};
#pragma unroll
        for (int j = 0; j < 4; ++j) {
            const int k = k4 * 4 + j;
            if (k < K) {
                float xval = xs4[j];
                if (FUSE_IN) xval = selu_f(di * xval + bprev[k]);  // prev-layer epilogue
#pragma unroll
                for (int f = 0; f < F; ++f) accf[f] = fmaf(xval, W[k * F + f], accf[f]);
            }
        }
    }
#pragma unroll
    for (int f = 0; f < F; ++f) accf[f] *= di;
    __half2* ro2 = reinterpret_cast<__half2*>(hs + (size_t)i * SO);
#pragma unroll
    for (int f2 = 0; f2 < F8 / 2; ++f2)
        ro2[f2] = __float22half2_rn(make_float2(accf[2 * f2], accf[2 * f2 + 1]));
}

// CSR gather on fp16 rows: G lanes/node, lane chunk = uint4 (8 halves), fp32 accum.
template <int F, int S /*halves*/, int G, int SOUT, bool LAST>
__global__ void k_agg(const int* __restrict__ rowptr, const int* __restrict__ csr,
                      const __half* __restrict__ hs, float* __restrict__ out,
                      const float* __restrict__ dinv, const float* __restrict__ bias,
                      int n) {
    constexpr int NPW = 64 / G;
    constexpr int CH = ((F + 7) & ~7) / 8;
    int lane = threadIdx.x & 63;
    int g = lane / G;
    int fl = lane & (G - 1);
    int wid = (blockIdx.x * BLK + threadIdx.x) >> 6;
    int d = wid * NPW + g;
    if (d >= n || fl >= CH) return;
    int beg = rowptr[d], end = rowptr[d + 1];
    auto rowp = [&](int r) {
        return reinterpret_cast<const uint4*>(hs + (size_t)r * S) + fl;
    };
    float s0[8], s1[8] = {0}, s2[8] = {0}, s3[8] = {0};
    h8_set(s0, *rowp(d));  // self
    int p = beg;
    for (; p + 4 <= end; p += 4) {
        int e0 = csr[p], e1 = csr[p + 1], e2 = csr[p + 2], e3 = csr[p + 3];
        uint4 v0 = *rowp(e0), v1 = *rowp(e1), v2 = *rowp(e2), v3 = *rowp(e3);
        h8_add(s0, v0); h8_add(s1, v1); h8_add(s2, v2); h8_add(s3, v3);
    }
    for (; p < end; ++p) h8_add(s0, *rowp(csr[p]));
    float sum[8];
#pragma unroll
    for (int j = 0; j < 8; ++j) sum[j] = (s0[j] + s1[j]) + (s2[j] + s3[j]);
    if (LAST) {
        float dv = dinv[d];
        float r[8];
#pragma unroll
        for (int j = 0; j < 8; ++j) {
            int col = fl * 8 + j;
            r[j] = (col < F) ? selu_f(dv * sum[j] + bias[col]) : 0.0f;
        }
        float* op = out + (size_t)d * F + fl * 8;
        *reinterpret_cast<float4*>(op) = make_float4(r[0], r[1], r[2], r[3]);
        if (fl * 8 + 4 < F)
            *reinterpret_cast<float4*>(op + 4) = make_float4(r[4], r[5], r[6], r[7]);
    } else {
        float* op = out + (size_t)d * SOUT + fl * 8;
        *reinterpret_cast<float4*>(op) = make_float4(sum[0], sum[1], sum[2], sum[3]);
        *reinterpret_cast<float4*>(op + 4) = make_float4(sum[4], sum[5], sum[6], sum[7]);
    }
}

extern "C" void kernel_launch(void* const* d_in, const int* in_sizes, int n_in,
                              void* d_out, int out_size, void* d_ws, size_t ws_size,
                              hipStream_t stream) {
    const float* x = (const float*)d_in[0];
    const int* ei = (const int*)d_in[1];  // int32 on device
    const float* W1 = (const float*)d_in[2];
    const float* b1 = (const float*)d_in[3];
    const float* W2 = (const float*)d_in[4];
    const float* b2 = (const float*)d_in[5];
    const float* W3 = (const float*)d_in[6];
    const float* b3 = (const float*)d_in[7];
    const float* W4 = (const float*)d_in[8];
    const float* b4 = (const float*)d_in[9];

    int n = in_sizes[0] / 128;
    int e = in_sizes[1] / 2;
    const int* s32 = ei;
    const int* d32 = ei + e;
    int nbkt = (n + CBN - 1) >> CBSH;  // 98 for n=100k (<= NCBC)

    char* w = (char*)d_ws;
    auto alloc = [&](size_t bytes) {
        char* p = w;
        w += (bytes + 255) & ~(size_t)255;
        return p;
    };
    int* deg = (int*)alloc((size_t)n * 4);
    int* rowptr = (int*)alloc(((size_t)n + 1) * 4);
    int* bsums = (int*)alloc((size_t)BLK * 4);
    float* dinv = (float*)alloc((size_t)n * 4);
    int* csr = (int*)alloc((size_t)e * 4);
    int* H = (int*)alloc((size_t)NB2 * nbkt * 4);
    int* bstart = (int*)alloc(((size_t)nbkt + 1) * 4);
    __half* bufA = (__half*)alloc((size_t)n * 40 * 2);  // hs (max stride 40h); aliases slab
    float* bufB = (float*)alloc((size_t)n * 32 * 4);    // agg out / gemm in (fp32)
    unsigned* slab = (unsigned*)bufA;  // e*4 = 6.4MB <= 8MB

    int nb = (n + BLK - 1) / BLK;
    int nb_scan = (n + BLK * 4 - 1) / (BLK * 4);  // 98 (<= 256)

    // CSR build: exact two-pass counting sort (no global atomics, tiny LDS)
    k_cnt<<<NB2, BLK, 0, stream>>>(d32, H, e, nbkt);
    k_bsum<<<1, BLK, 0, stream>>>(H, bstart, nbkt, e);
    k_off<<<nbkt, BLK, 0, stream>>>(H, bstart, nbkt);
    k_scatter2<<<NB2, BLK, 0, stream>>>(s32, d32, H, slab, e, nbkt);
    k_histB<<<nbkt, BLK, 0, stream>>>(bstart, slab, deg, n);
    k_scan1<<<nb_scan, BLK, 0, stream>>>(deg, rowptr, bsums, n);
    k_scan2<<<1, BLK, 0, stream>>>(bsums, nb_scan);
    k_scan3<<<nb, BLK, 0, stream>>>(rowptr, bsums, deg, dinv, n, e);
    k_placeC<<<nbkt, BLK, 0, stream>>>(bstart, slab, rowptr, csr, n);

    // agg grids: nodes/block = 4 waves * (64/G)
    int ab1 = (n + 127) / 128;  // G=2
    int ab2 = (n + 63) / 64;    // G=4
    int ab4 = (n + 31) / 32;    // G=8

    // layer 1: x[.,128] @ W1 -> hs1 fp16 (stride 16h); agg -> bufB fp32 (stride 16)
    k_gemm<128, 128, 15, 128, 16, false><<<nb, BLK, 0, stream>>>(x, W1, nullptr, dinv, bufA, n);
    k_agg<15, 16, 2, 16, false><<<ab1, BLK, 0, stream>>>(rowptr, csr, bufA, bufB, dinv, nullptr, n);

    // layer 2: hs2 stride 32h; agg out stride 32
    k_gemm<15, 16, 20, 16, 32, true><<<nb, BLK, 0, stream>>>(bufB, W2, b1, dinv, bufA, n);
    k_agg<20, 32, 4, 32, false><<<ab2, BLK, 0, stream>>>(rowptr, csr, bufA, bufB, dinv, nullptr, n);

    // layer 3
    k_gemm<20, 20, 27, 32, 32, true><<<nb, BLK, 0, stream>>>(bufB, W3, b2, dinv, bufA, n);
    k_agg<27, 32, 4, 32, false><<<ab2, BLK, 0, stream>>>(rowptr, csr, bufA, bufB, dinv, nullptr, n);

    // layer 4: hs4 stride 40h (80B rows, always 2 lines); agg fuses final epilogue -> d_out
    k_gemm<27, 28, 36, 32, 40, true><<<nb, BLK, 0, stream>>>(bufB, W4, b3, dinv, bufA, n);
    k_agg<36, 40, 8, 36, true><<<ab4, BLK, 0, stream>>>(rowptr, csr, bufA, (float*)d_out, dinv, b4, n);
}

// Round 9
// 277.386 us; speedup vs baseline: 1.6105x; 1.0211x over previous
//
#include <hip/hip_runtime.h>
#include <hip/hip_fp16.h>
#include <math.h>

#define BLK 256
#define CBSH 9           // 512 nodes per coarse bucket (196 buckets for n=100k)
#define CBN 512
#define NCBC 256         // static LDS sizing (nbkt <= 256)
#define NB2 512          // blocks for count/scatter passes

__device__ __forceinline__ float selu_f(float x) {
    const float kScale = 1.0507009873554805f;
    const float kAlpha = 1.6732632423543772f;
    return x > 0.0f ? kScale * x : kScale * kAlpha * expm1f(x);
}

__device__ __forceinline__ float2 h2f2(unsigned u) {
    __half2 h = *reinterpret_cast<__half2*>(&u);
    return __half22float2(h);
}
__device__ __forceinline__ void h8_set(float* a, uint4 v) {
    float2 f0 = h2f2(v.x), f1 = h2f2(v.y), f2 = h2f2(v.z), f3 = h2f2(v.w);
    a[0] = f0.x; a[1] = f0.y; a[2] = f1.x; a[3] = f1.y;
    a[4] = f2.x; a[5] = f2.y; a[6] = f3.x; a[7] = f3.y;
}
__device__ __forceinline__ void h8_add(float* a, uint4 v) {
    float2 f0 = h2f2(v.x), f1 = h2f2(v.y), f2 = h2f2(v.z), f3 = h2f2(v.w);
    a[0] += f0.x; a[1] += f0.y; a[2] += f1.x; a[3] += f1.y;
    a[4] += f2.x; a[5] += f2.y; a[6] += f3.x; a[7] += f3.y;
}

// Pass A: per-block histogram over coarse buckets -> H[block][bucket]
__global__ void k_cnt(const int* __restrict__ dst, int* __restrict__ H, int e, int nbkt) {
    __shared__ int hist[NCBC];
    int tid = threadIdx.x;
    for (int b = tid; b < nbkt; b += BLK) hist[b] = 0;
    __syncthreads();
    int per = (e + NB2 - 1) / NB2;
    int lo = blockIdx.x * per;
    int hi = min(e, lo + per);
    for (int i = lo + tid; i < hi; i += BLK) atomicAdd(&hist[dst[i] >> CBSH], 1);
    __syncthreads();
    for (int b = tid; b < nbkt; b += BLK) H[blockIdx.x * nbkt + b] = hist[b];
}

// Column totals + exclusive scan over buckets -> bstart[nbkt+1]
__global__ void k_bsum(const int* __restrict__ H, int* __restrict__ bstart, int nbkt, int e) {
    __shared__ int tot[NCBC];
    int tid = threadIdx.x;
    for (int b = tid; b < nbkt; b += BLK) {
        int s = 0;
        for (int i = 0; i < NB2; ++i) s += H[i * nbkt + b];
        tot[b] = s;
    }
    __syncthreads();
    if (tid == 0) {
        int acc = 0;
        for (int b = 0; b < nbkt; ++b) {
            bstart[b] = acc;
            acc += tot[b];
        }
        bstart[nbkt] = acc;  // == e
    }
}

// Per-bucket exclusive scan over blocks (in-place): H[i][b] <- bstart[b] + sum_{i'<i} H[i'][b]
__global__ void k_off(int* __restrict__ H, const int* __restrict__ bstart, int nbkt) {
    __shared__ int lds[BLK];
    int b = blockIdx.x, tid = threadIdx.x;
    int v0 = H[(2 * tid) * nbkt + b];
    int v1 = H[(2 * tid + 1) * nbkt + b];
    int pair = v0 + v1;
    lds[tid] = pair;
    __syncthreads();
    int val = pair;
    for (int off = 1; off < BLK; off <<= 1) {
        int t2 = (tid >= off) ? lds[tid - off] : 0;
        __syncthreads();
        val += t2;
        lds[tid] = val;
        __syncthreads();
    }
    int excl = val - pair + bstart[b];
    H[(2 * tid) * nbkt + b] = excl;
    H[(2 * tid + 1) * nbkt + b] = excl + v0;
}

// Pass B: re-read edges, place into exact per-(block,bucket) regions via LDS cursors.
// pack = (src<<CBSH) | (dst&(CBN-1))  (17+9 = 26 bits)
__global__ void k_scatter2(const int* __restrict__ src, const int* __restrict__ dst,
                           const int* __restrict__ H, unsigned* __restrict__ slab,
                           int e, int nbkt) {
    __shared__ int cur[NCBC];
    int tid = threadIdx.x;
    for (int b = tid; b < nbkt; b += BLK) cur[b] = H[blockIdx.x * nbkt + b];
    __syncthreads();
    int per = (e + NB2 - 1) / NB2;
    int lo = blockIdx.x * per;
    int hi = min(e, lo + per);
    for (int i = lo + tid; i < hi; i += BLK) {
        int s = src[i], d = dst[i];
        int b = d >> CBSH;
        int pos = atomicAdd(&cur[b], 1);
        slab[pos] = ((unsigned)s << CBSH) | (unsigned)(d & (CBN - 1));
    }
}

// One block per bucket: LDS hist -> LDS scan -> rowptr/dinv -> LDS-cursor place.
// rowptr[node] = bstart[b] + local exclusive scan (bucket's global edge offset known).
__global__ void k_build(const int* __restrict__ bstart, const unsigned* __restrict__ slab,
                        int* __restrict__ rowptr, float* __restrict__ dinv,
                        int* __restrict__ csr, int n, int e) {
    __shared__ int hist[CBN];     // counts, then cursors
    __shared__ int stmp[BLK];
    int b = blockIdx.x, tid = threadIdx.x;
    hist[2 * tid] = 0;
    hist[2 * tid + 1] = 0;
    __syncthreads();
    int lo = bstart[b], hi = bstart[b + 1];
    for (int i = lo + tid; i < hi; i += BLK) atomicAdd(&hist[slab[i] & (CBN - 1)], 1);
    __syncthreads();
    int h0 = hist[2 * tid], h1 = hist[2 * tid + 1];
    int pair = h0 + h1;
    stmp[tid] = pair;
    __syncthreads();
    int val = pair;
    for (int off = 1; off < BLK; off <<= 1) {
        int t2 = (tid >= off) ? stmp[tid - off] : 0;
        __syncthreads();
        val += t2;
        stmp[tid] = val;
        __syncthreads();
    }
    int e0 = lo + val - pair;      // cursor start for node 2*tid
    int e1 = e0 + h0;
    hist[2 * tid] = e0;
    hist[2 * tid + 1] = e1;
    int node0 = b << CBSH;
    int nA = node0 + 2 * tid, nB = nA + 1;
    if (nA < n) { rowptr[nA] = e0; dinv[nA] = rsqrtf((float)(h0 + 1)); }
    if (nB < n) { rowptr[nB] = e1; dinv[nB] = rsqrtf((float)(h1 + 1)); }
    if (b == 0 && tid == 0) rowptr[n] = e;  // sentinel
    __syncthreads();
    for (int i = lo + tid; i < hi; i += BLK) {
        unsigned p = slab[i];
        int pos = atomicAdd(&hist[p & (CBN - 1)], 1);
        csr[pos] = (int)(p >> CBSH);
    }
}

// hs[i,0..F) = fp16( dinv[i] * (act(xin[i,0..K)) @ W) ); rows at SO halves, zero-pad to F8.
template <int K, int KP, int F, int SI, int SO, bool FUSE_IN>
__global__ void k_gemm(const float* __restrict__ xin, const float* __restrict__ W,
                       const float* __restrict__ bprev, const float* __restrict__ dinv,
                       __half* __restrict__ hs, int n) {
    constexpr int F8 = (F + 7) & ~7;
    int i = blockIdx.x * BLK + threadIdx.x;
    if (i >= n) return;
    const float* xr = xin + (size_t)i * SI;
    float di = dinv[i];
    float accf[F8];
#pragma unroll
    for (int f = 0; f < F8; ++f) accf[f] = 0.0f;
#pragma unroll
    for (int k4 = 0; k4 < KP / 4; ++k4) {
        float4 xv = *reinterpret_cast<const float4*>(xr + k4 * 4);
        float xs4[4] = {xv.x, xv.y, xv.z, xv.w};
#pragma unroll
        for (int j = 0; j < 4; ++j) {
            const int k = k4 * 4 + j;
            if (k < K) {
                float xval = xs4[j];
                if (FUSE_IN) xval = selu_f(di * xval + bprev[k]);  // prev-layer epilogue
#pragma unroll
                for (int f = 0; f < F; ++f) accf[f] = fmaf(xval, W[k * F + f], accf[f]);
            }
        }
    }
#pragma unroll
    for (int f = 0; f < F; ++f) accf[f] *= di;
    __half2* ro2 = reinterpret_cast<__half2*>(hs + (size_t)i * SO);
#pragma unroll
    for (int f2 = 0; f2 < F8 / 2; ++f2)
        ro2[f2] = __float22half2_rn(make_float2(accf[2 * f2], accf[2 * f2 + 1]));
}

// Layer-4 gemm: split output — main 32 feats (stride 32h, 1 line) + tail 4 feats (stride 8h).
__global__ void k_gemm4(const float* __restrict__ xin, const float* __restrict__ W,
                        const float* __restrict__ bprev, const float* __restrict__ dinv,
                        __half* __restrict__ hsm, __half* __restrict__ hst, int n) {
    constexpr int K = 27, F = 36;
    int i = blockIdx.x * BLK + threadIdx.x;
    if (i >= n) return;
    const float* xr = xin + (size_t)i * 32;
    float di = dinv[i];
    float accf[40];
#pragma unroll
    for (int f = 0; f < 40; ++f) accf[f] = 0.0f;
#pragma unroll
    for (int k4 = 0; k4 < 7; ++k4) {
        float4 xv = *reinterpret_cast<const float4*>(xr + k4 * 4);
        float xs4[4] = {xv.x, xv.y, xv.z, xv.w};
#pragma unroll
        for (int j = 0; j < 4; ++j) {
            const int k = k4 * 4 + j;
            if (k < K) {
                float xval = selu_f(di * xv.x + bprev[k]);
                xval = selu_f(di * xs4[j] + bprev[k]);
#pragma unroll
                for (int f = 0; f < F; ++f) accf[f] = fmaf(xval, W[k * F + f], accf[f]);
            }
        }
    }
#pragma unroll
    for (int f = 0; f < F; ++f) accf[f] *= di;
    __half2* rm = reinterpret_cast<__half2*>(hsm + (size_t)i * 32);
#pragma unroll
    for (int f2 = 0; f2 < 16; ++f2)
        rm[f2] = __float22half2_rn(make_float2(accf[2 * f2], accf[2 * f2 + 1]));
    __half2* rt = reinterpret_cast<__half2*>(hst + (size_t)i * 8);
#pragma unroll
    for (int f2 = 0; f2 < 4; ++f2)
        rt[f2] = __float22half2_rn(make_float2(accf[32 + 2 * f2], accf[32 + 2 * f2 + 1]));
}

// CSR gather on fp16 rows: G lanes/node, lane chunk = uint4 (8 halves), fp32 accum.
// Unroll-8 folded into 4 accumulators; csr via non-temporal loads.
template <int F, int S /*halves*/, int G, int SOUT>
__global__ void k_agg(const int* __restrict__ rowptr, const int* __restrict__ csr,
                      const __half* __restrict__ hs, float* __restrict__ out, int n) {
    constexpr int NPW = 64 / G;
    constexpr int CH = ((F + 7) & ~7) / 8;
    int lane = threadIdx.x & 63;
    int g = lane / G;
    int fl = lane & (G - 1);
    int wid = (blockIdx.x * BLK + threadIdx.x) >> 6;
    int d = wid * NPW + g;
    if (d >= n || fl >= CH) return;
    int beg = rowptr[d], end = rowptr[d + 1];
    auto rowp = [&](int r) {
        return reinterpret_cast<const uint4*>(hs + (size_t)r * S) + fl;
    };
    float s0[8], s1[8] = {0}, s2[8] = {0}, s3[8] = {0};
    h8_set(s0, *rowp(d));  // self
    int p = beg;
    for (; p + 8 <= end; p += 8) {
        int e0 = __builtin_nontemporal_load(csr + p);
        int e1 = __builtin_nontemporal_load(csr + p + 1);
        int e2 = __builtin_nontemporal_load(csr + p + 2);
        int e3 = __builtin_nontemporal_load(csr + p + 3);
        int e4 = __builtin_nontemporal_load(csr + p + 4);
        int e5 = __builtin_nontemporal_load(csr + p + 5);
        int e6 = __builtin_nontemporal_load(csr + p + 6);
        int e7 = __builtin_nontemporal_load(csr + p + 7);
        uint4 v0 = *rowp(e0), v1 = *rowp(e1), v2 = *rowp(e2), v3 = *rowp(e3);
        uint4 v4 = *rowp(e4), v5 = *rowp(e5), v6 = *rowp(e6), v7 = *rowp(e7);
        h8_add(s0, v0); h8_add(s1, v1); h8_add(s2, v2); h8_add(s3, v3);
        h8_add(s0, v4); h8_add(s1, v5); h8_add(s2, v6); h8_add(s3, v7);
    }
    for (; p + 4 <= end; p += 4) {
        int e0 = __builtin_nontemporal_load(csr + p);
        int e1 = __builtin_nontemporal_load(csr + p + 1);
        int e2 = __builtin_nontemporal_load(csr + p + 2);
        int e3 = __builtin_nontemporal_load(csr + p + 3);
        uint4 v0 = *rowp(e0), v1 = *rowp(e1), v2 = *rowp(e2), v3 = *rowp(e3);
        h8_add(s0, v0); h8_add(s1, v1); h8_add(s2, v2); h8_add(s3, v3);
    }
    for (; p < end; ++p) h8_add(s0, *rowp(__builtin_nontemporal_load(csr + p)));
    float sum[8];
#pragma unroll
    for (int j = 0; j < 8; ++j) sum[j] = (s0[j] + s1[j]) + (s2[j] + s3[j]);
    float* op = out + (size_t)d * SOUT + fl * 8;
    *reinterpret_cast<float4*>(op) = make_float4(sum[0], sum[1], sum[2], sum[3]);
    *reinterpret_cast<float4*>(op + 4) = make_float4(sum[4], sum[5], sum[6], sum[7]);
}

// Layer-4 agg on split hs (main stride 32h + tail stride 8h), fused final epilogue.
__global__ void k_agg4(const int* __restrict__ rowptr, const int* __restrict__ csr,
                       const __half* __restrict__ hsm, const __half* __restrict__ hst,
                       float* __restrict__ out, const float* __restrict__ dinv,
                       const float* __restrict__ bias, int n) {
    constexpr int G = 8, NPW = 8;
    int lane = threadIdx.x & 63;
    int g = lane / G;
    int fl = lane & (G - 1);
    int wid = (blockIdx.x * BLK + threadIdx.x) >> 6;
    int d = wid * NPW + g;
    if (d >= n || fl >= 5) return;
    int beg = rowptr[d], end = rowptr[d + 1];
    const __half* bp = (fl < 4) ? hsm + fl * 8 : hst;
    int mul = (fl < 4) ? 32 : 8;
    auto rowp = [&](int r) {
        return reinterpret_cast<const uint4*>(bp + (size_t)r * mul);
    };
    float s0[8], s1[8] = {0}, s2[8] = {0}, s3[8] = {0};
    h8_set(s0, *rowp(d));  // self
    int p = beg;
    for (; p + 8 <= end; p += 8) {
        int e0 = __builtin_nontemporal_load(csr + p);
        int e1 = __builtin_nontemporal_load(csr + p + 1);
        int e2 = __builtin_nontemporal_load(csr + p + 2);
        int e3 = __builtin_nontemporal_load(csr + p + 3);
        int e4 = __builtin_nontemporal_load(csr + p + 4);
        int e5 = __builtin_nontemporal_load(csr + p + 5);
        int e6 = __builtin_nontemporal_load(csr + p + 6);
        int e7 = __builtin_nontemporal_load(csr + p + 7);
        uint4 v0 = *rowp(e0), v1 = *rowp(e1), v2 = *rowp(e2), v3 = *rowp(e3);
        uint4 v4 = *rowp(e4), v5 = *rowp(e5), v6 = *rowp(e6), v7 = *rowp(e7);
        h8_add(s0, v0); h8_add(s1, v1); h8_add(s2, v2); h8_add(s3, v3);
        h8_add(s0, v4); h8_add(s1, v5); h8_add(s2, v6); h8_add(s3, v7);
    }
    for (; p + 4 <= end; p += 4) {
        int e0 = __builtin_nontemporal_load(csr + p);
        int e1 = __builtin_nontemporal_load(csr + p + 1);
        int e2 = __builtin_nontemporal_load(csr + p + 2);
        int e3 = __builtin_nontemporal_load(csr + p + 3);
        uint4 v0 = *rowp(e0), v1 = *rowp(e1), v2 = *rowp(e2), v3 = *rowp(e3);
        h8_add(s0, v0); h8_add(s1, v1); h8_add(s2, v2); h8_add(s3, v3);
    }
    for (; p < end; ++p) h8_add(s0, *rowp(__builtin_nontemporal_load(csr + p)));
    float dv = dinv[d];
    float r[8];
#pragma unroll
    for (int j = 0; j < 8; ++j) {
        float sum = (s0[j] + s1[j]) + (s2[j] + s3[j]);
        int col = (fl < 4) ? fl * 8 + j : 32 + j;
        r[j] = (col < 36) ? selu_f(dv * sum + bias[col]) : 0.0f;
    }
    if (fl < 4) {
        float* op = out + (size_t)d * 36 + fl * 8;
        *reinterpret_cast<float4*>(op) = make_float4(r[0], r[1], r[2], r[3]);
        *reinterpret_cast<float4*>(op + 4) = make_float4(r[4], r[5], r[6], r[7]);
    } else {
        float* op = out + (size_t)d * 36 + 32;
        *reinterpret_cast<float4*>(op) = make_float4(r[0], r[1], r[2], r[3]);
    }
}

extern "C" void kernel_launch(void* const* d_in, const int* in_sizes, int n_in,
                              void* d_out, int out_size, void* d_ws, size_t ws_size,
                              hipStream_t stream) {
    const float* x = (const float*)d_in[0];
    const int* ei = (const int*)d_in[1];  // int32 on device
    const float* W1 = (const float*)d_in[2];
    const float* b1 = (const float*)d_in[3];
    const float* W2 = (const float*)d_in[4];
    const float* b2 = (const float*)d_in[5];
    const float* W3 = (const float*)d_in[6];
    const float* b3 = (const float*)d_in[7];
    const float* W4 = (const float*)d_in[8];
    const float* b4 = (const float*)d_in[9];

    int n = in_sizes[0] / 128;
    int e = in_sizes[1] / 2;
    const int* s32 = ei;
    const int* d32 = ei + e;
    int nbkt = (n + CBN - 1) >> CBSH;  // 196 for n=100k (<= NCBC)

    char* w = (char*)d_ws;
    auto alloc = [&](size_t bytes) {
        char* p = w;
        w += (bytes + 255) & ~(size_t)255;
        return p;
    };
    int* rowptr = (int*)alloc(((size_t)n + 1) * 4);
    float* dinv = (float*)alloc((size_t)n * 4);
    int* csr = (int*)alloc((size_t)e * 4);
    int* H = (int*)alloc((size_t)NB2 * nbkt * 4);
    int* bstart = (int*)alloc(((size_t)nbkt + 1) * 4);
    __half* bufA = (__half*)alloc((size_t)n * 40 * 2);  // hs; aliases slab
    float* bufB = (float*)alloc((size_t)n * 32 * 4);    // agg out / gemm in (fp32)
    unsigned* slab = (unsigned*)bufA;   // e*4 = 6.4MB <= 8MB
    __half* hsm = bufA;                 // layer-4 main: n*32h = 6.4MB
    __half* hst = bufA + (size_t)n * 32;  // layer-4 tail: n*8h = 1.6MB

    int nb = (n + BLK - 1) / BLK;

    // CSR build: exact two-pass counting sort + fused build
    k_cnt<<<NB2, BLK, 0, stream>>>(d32, H, e, nbkt);
    k_bsum<<<1, BLK, 0, stream>>>(H, bstart, nbkt, e);
    k_off<<<nbkt, BLK, 0, stream>>>(H, bstart, nbkt);
    k_scatter2<<<NB2, BLK, 0, stream>>>(s32, d32, H, slab, e, nbkt);
    k_build<<<nbkt, BLK, 0, stream>>>(bstart, slab, rowptr, dinv, csr, n, e);

    // agg grids: nodes/block = 4 waves * (64/G)
    int ab1 = (n + 127) / 128;  // G=2
    int ab2 = (n + 63) / 64;    // G=4
    int ab4 = (n + 31) / 32;    // G=8 (layer 4)

    // layer 1: x[.,128] @ W1 -> hs1 fp16 (stride 16h); agg -> bufB fp32 (stride 16)
    k_gemm<128, 128, 15, 128, 16, false><<<nb, BLK, 0, stream>>>(x, W1, nullptr, dinv, bufA, n);
    k_agg<15, 16, 2, 16><<<ab1, BLK, 0, stream>>>(rowptr, csr, bufA, bufB, n);

    // layer 2: hs2 stride 32h; agg out stride 32
    k_gemm<15, 16, 20, 16, 32, true><<<nb, BLK, 0, stream>>>(bufB, W2, b1, dinv, bufA, n);
    k_agg<20, 32, 4, 32><<<ab2, BLK, 0, stream>>>(rowptr, csr, bufA, bufB, n);

    // layer 3
    k_gemm<20, 20, 27, 32, 32, true><<<nb, BLK, 0, stream>>>(bufB, W3, b2, dinv, bufA, n);
    k_agg<27, 32, 4, 32><<<ab2, BLK, 0, stream>>>(rowptr, csr, bufA, bufB, n);

    // layer 4: split hs (main 32h + tail 8h); agg fuses final epilogue -> d_out
    k_gemm4<<<nb, BLK, 0, stream>>>(bufB, W4, b3, dinv, hsm, hst, n);
    k_agg4<<<ab4, BLK, 0, stream>>>(rowptr, csr, hsm, hst, (float*)d_out, dinv, b4, n);
}